// Round 5
// baseline (192.829 us; speedup 1.0000x reference)
//
#include <hip/hip_runtime.h>
#include <hip/hip_bf16.h>
#include <math.h>

#define B_ROWS 16384
#define C_COLS 1000
#define C_PAD  1024
#define FDIM   1024
#define FBLKS  4096           // feature normalize blocks (4 rows each)

typedef __attribute__((ext_vector_type(8))) short bf16x8;
typedef __attribute__((ext_vector_type(4))) float f32x4;

// async global->LDS, 16B per lane; lds dst is wave-uniform base (HW puts lane i at base + i*16)
#define GLD_LDS(gp, lp) __builtin_amdgcn_global_load_lds( \
    (__attribute__((address_space(1))) void*)(gp),        \
    (__attribute__((address_space(3))) void*)(lp), 16, 0, 0)

// ---------------- fused row L2-normalize fp32 -> bf16 (one wave per row) ----------------
__global__ __launch_bounds__(256) void normalize_all(
    const float* __restrict__ feat, const float* __restrict__ prot,
    __hip_bfloat16* __restrict__ fb, __hip_bfloat16* __restrict__ pb)
{
    const int lane = threadIdx.x & 63;
    const int wave = threadIdx.x >> 6;

    const float* in;
    __hip_bfloat16* out;
    int row, nvalid;
    if (blockIdx.x < FBLKS) {
        row = blockIdx.x * 4 + wave;  in = feat; out = fb; nvalid = B_ROWS;
    } else {
        row = (blockIdx.x - FBLKS) * 4 + wave;  in = prot; out = pb; nvalid = C_COLS;
    }
    __hip_bfloat16* orow = out + (size_t)row * FDIM;

    if (row >= nvalid) {               // zero-pad prototype rows 1000..1023
        ushort4 z = make_ushort4(0, 0, 0, 0);
        #pragma unroll
        for (int c = 0; c < 4; ++c) ((ushort4*)orow)[lane + c * 64] = z;
        return;
    }

    const float4* rp = (const float4*)(in + (size_t)row * FDIM);
    float4 v[4];
    float ss = 0.0f;
    #pragma unroll
    for (int c = 0; c < 4; ++c) {
        v[c] = rp[lane + c * 64];
        ss += v[c].x * v[c].x + v[c].y * v[c].y + v[c].z * v[c].z + v[c].w * v[c].w;
    }
    #pragma unroll
    for (int off = 1; off < 64; off <<= 1) ss += __shfl_xor(ss, off, 64);
    const float inv = 1.0f / sqrtf(fmaxf(ss, 1e-24f));

    #pragma unroll
    for (int c = 0; c < 4; ++c) {
        __hip_bfloat16 o[4];
        o[0] = __float2bfloat16(v[c].x * inv);
        o[1] = __float2bfloat16(v[c].y * inv);
        o[2] = __float2bfloat16(v[c].z * inv);
        o[3] = __float2bfloat16(v[c].w * inv);
        ((ushort4*)orow)[lane + c * 64] = *(ushort4*)o;
    }
}

// ---------------- bf16 GEMM 128x128, BK=32, double-buffered LDS, 1 barrier/iter -----------
// LDS tile [128 rows][32 k] per buffer; row stride 32 elems (64 B).
// Logical k-octet q (0..3) stored at phys slot (q ^ ((row>>1)&3)) -> per-quarter reads
// cover all eight 16B offsets twice => 2-way (free).
__global__ __launch_bounds__(256) void gemm_dist(
    const __hip_bfloat16* __restrict__ A,
    const __hip_bfloat16* __restrict__ Bp,
    __hip_bfloat16* __restrict__ D,
    float* __restrict__ rowsum)
{
    __shared__ __hip_bfloat16 As[2][128 * 32];   // 2 x 8 KB
    __shared__ __hip_bfloat16 Bs[2][128 * 32];   // 2 x 8 KB

    const int tid  = threadIdx.x;
    const int lane = tid & 63;
    const int wave = tid >> 6;

    // XCD swizzle: the 8 bn-blocks of one bm share id%8 (same XCD) for A-tile L2 reuse
    const int id  = blockIdx.x;             // 0..1023
    const int xcd = id & 7;
    const int seq = id >> 3;                // 0..127
    const int bn  = seq & 7;                // 0..7
    const int bm  = xcd * 16 + (seq >> 3);  // 0..127

    const int waveM = (wave >> 1) * 64;
    const int waveN = (wave & 1) * 64;

    f32x4 acc[4][4] = {};

    // staging: chunk = 16 rows x 32 k (1 KB); wave w stages A chunks {2w,2w+1}, B chunks {2w,2w+1}.
    // lane i -> local row r = i>>2, phys slot p = i&3, fetching logical octet q = p ^ ((r>>1)&3)
    const int srow = lane >> 2;
    const int sq   = (lane & 3) ^ ((srow >> 1) & 3);
    const __hip_bfloat16* Abase = A  + ((size_t)(bm * 128) + wave * 32 + srow) * FDIM + sq * 8;
    const __hip_bfloat16* Bbase = Bp + ((size_t)(bn * 128) + wave * 32 + srow) * FDIM + sq * 8;

    #define STAGE(koff, b) do {                                              \
        GLD_LDS(Abase + (size_t)(koff),             &As[b][wave * 1024]);        \
        GLD_LDS(Abase + (size_t)(koff) + 16 * FDIM, &As[b][wave * 1024 + 512]);  \
        GLD_LDS(Bbase + (size_t)(koff),             &Bs[b][wave * 1024]);        \
        GLD_LDS(Bbase + (size_t)(koff) + 16 * FDIM, &Bs[b][wave * 1024 + 512]);  \
    } while (0)

    STAGE(0, 0);
    __syncthreads();

    const int q = lane >> 4;                // logical k-octet 0..3 within BK=32
    #pragma unroll 2
    for (int k = 0; k < 32; ++k) {
        const int cur = k & 1;
        if (k < 31) STAGE((k + 1) * 32, cur ^ 1);   // prefetch next chunk into other buffer

        bf16x8 a[4], b[4];
        #pragma unroll
        for (int mt = 0; mt < 4; ++mt) {
            const int R = waveM + mt * 16 + (lane & 15);
            a[mt] = *(const bf16x8*)&As[cur][R * 32 + ((q ^ ((R >> 1) & 3)) * 8)];
        }
        #pragma unroll
        for (int nt = 0; nt < 4; ++nt) {
            const int R = waveN + nt * 16 + (lane & 15);
            b[nt] = *(const bf16x8*)&Bs[cur][R * 32 + ((q ^ ((R >> 1) & 3)) * 8)];
        }
        #pragma unroll
        for (int mt = 0; mt < 4; ++mt)
            #pragma unroll
            for (int nt = 0; nt < 4; ++nt)
                acc[mt][nt] = __builtin_amdgcn_mfma_f32_16x16x32_bf16(a[mt], b[nt], acc[mt][nt], 0, 0, 0);

        __syncthreads();   // one barrier/iter: drains loads issued a full iteration ago
    }

    // epilogue: d = sqrt(max(1 - sim, 0)); C/D layout: col = lane&15, row = (lane>>4)*4 + reg
    const int row0 = bm * 128 + waveM;
    const int col0 = bn * 128 + waveN;
    #pragma unroll
    for (int mt = 0; mt < 4; ++mt) {
        #pragma unroll
        for (int r = 0; r < 4; ++r) {
            const int row = row0 + mt * 16 + (lane >> 4) * 4 + r;
            float part = 0.0f;
            #pragma unroll
            for (int nt = 0; nt < 4; ++nt) {
                const int col = col0 + nt * 16 + (lane & 15);
                const float sim = acc[mt][nt][r];
                const float dv = sqrtf(fmaxf(1.0f - sim, 0.0f));
                if (col < C_COLS) {
                    D[(size_t)row * C_COLS + col] = __float2bfloat16(dv);
                    part += dv;
                }
            }
            part += __shfl_xor(part, 1, 64);
            part += __shfl_xor(part, 2, 64);
            part += __shfl_xor(part, 4, 64);
            part += __shfl_xor(part, 8, 64);
            if ((lane & 15) == 0) atomicAdd(&rowsum[row], part);
        }
    }
}

// ---------------- finalize: out = (-|ds|/T) * (d + rowsum/1000) ----------------
__global__ __launch_bounds__(256) void finalize(
    const __hip_bfloat16* __restrict__ D, const float* __restrict__ rowsum,
    const float* __restrict__ scale, const float* __restrict__ temp,
    float* __restrict__ out)
{
    const size_t i = (size_t)blockIdx.x * 256 + threadIdx.x;   // 8-element group
    const float a = -fabsf(scale[0]) / temp[0];
    const int row = (int)((i * 8) / C_COLS);                   // 1000 % 8 == 0, no straddle
    const float m = rowsum[row] * (1.0f / (float)C_COLS);

    const bf16x8 dv = *(const bf16x8*)(D + i * 8);
    const __hip_bfloat16* dp = (const __hip_bfloat16*)&dv;
    float4 o0, o1;
    o0.x = a * (__bfloat162float(dp[0]) + m);
    o0.y = a * (__bfloat162float(dp[1]) + m);
    o0.z = a * (__bfloat162float(dp[2]) + m);
    o0.w = a * (__bfloat162float(dp[3]) + m);
    o1.x = a * (__bfloat162float(dp[4]) + m);
    o1.y = a * (__bfloat162float(dp[5]) + m);
    o1.z = a * (__bfloat162float(dp[6]) + m);
    o1.w = a * (__bfloat162float(dp[7]) + m);
    ((float4*)out)[i * 2]     = o0;
    ((float4*)out)[i * 2 + 1] = o1;
}

extern "C" void kernel_launch(void* const* d_in, const int* in_sizes, int n_in,
                              void* d_out, int out_size, void* d_ws, size_t ws_size,
                              hipStream_t stream)
{
    const float* features = (const float*)d_in[0];   // [16384,1024]
    const float* protos   = (const float*)d_in[1];   // [1000,1024]
    const float* dscale   = (const float*)d_in[2];   // [1]
    const float* temp     = (const float*)d_in[3];   // [1]
    float* out = (float*)d_out;                      // [16384,1000]

    char* ws = (char*)d_ws;
    __hip_bfloat16* fb = (__hip_bfloat16*)ws;                     // 33,554,432 B
    __hip_bfloat16* pb = (__hip_bfloat16*)(ws + 33554432);        //  2,097,152 B
    __hip_bfloat16* D  = (__hip_bfloat16*)(ws + 35651584);        // 32,768,000 B
    float* rowsum      = (float*)(ws + 68419584);                 //     65,536 B

    hipMemsetAsync(rowsum, 0, B_ROWS * sizeof(float), stream);

    normalize_all<<<FBLKS + C_PAD / 4, 256, 0, stream>>>(features, protos, fb, pb);

    gemm_dist<<<1024, 256, 0, stream>>>(fb, pb, D, rowsum);

    finalize<<<(B_ROWS * C_COLS / 8) / 256, 256, 0, stream>>>(D, rowsum, dscale, temp, out);
}

// Round 6
// 160.623 us; speedup vs baseline: 1.2005x; 1.2005x over previous
//
#include <hip/hip_runtime.h>
#include <hip/hip_bf16.h>
#include <math.h>

#define B_ROWS 16384
#define C_COLS 1000
#define C_PAD  1024
#define FDIM   1024
#define FBLKS  4096           // feature normalize blocks (4 rows each)
#define FP8_SCALE 256.0f      // pre-scale before e4m3 quant (avoids subnormals)
#define INV_SIM   (1.0f / (FP8_SCALE * FP8_SCALE))

typedef __attribute__((ext_vector_type(8))) short bf16x8;
typedef __attribute__((ext_vector_type(4))) float f32x4;
typedef __attribute__((ext_vector_type(4))) int   i32x4;
typedef __attribute__((ext_vector_type(8))) int   i32x8;

// async global->LDS, 16B per lane; lds dst is wave-uniform base (HW puts lane i at base + i*16)
#define GLD_LDS(gp, lp) __builtin_amdgcn_global_load_lds( \
    (__attribute__((address_space(1))) void*)(gp),        \
    (__attribute__((address_space(3))) void*)(lp), 16, 0, 0)

// ---------------- fused row L2-normalize fp32 -> fp8 e4m3 (x256), one wave per row ---------
__global__ __launch_bounds__(256) void normalize_all(
    const float* __restrict__ feat, const float* __restrict__ prot,
    unsigned char* __restrict__ fb, unsigned char* __restrict__ pb,
    float* __restrict__ rowsum)
{
    const int lane = threadIdx.x & 63;
    const int wave = threadIdx.x >> 6;

    // fold rowsum zeroing into the first 64 blocks (replaces the memset dispatch)
    if (blockIdx.x < 64) rowsum[blockIdx.x * 256 + threadIdx.x] = 0.0f;

    const float* in;
    unsigned char* out;
    int row, nvalid;
    if (blockIdx.x < FBLKS) {
        row = blockIdx.x * 4 + wave;  in = feat; out = fb; nvalid = B_ROWS;
    } else {
        row = (blockIdx.x - FBLKS) * 4 + wave;  in = prot; out = pb; nvalid = C_COLS;
    }
    unsigned char* orow = out + (size_t)row * FDIM;

    if (row >= nvalid) {               // zero-pad prototype rows 1000..1023
        i32x4 z = {0, 0, 0, 0};
        ((i32x4*)orow)[lane] = z;      // 64 lanes x 16 B = 1024 B row
        return;
    }

    // lane owns 16 contiguous elements -> one 16 B fp8 store
    const float4* rp = (const float4*)(in + (size_t)row * FDIM);
    float4 v[4];
    float ss = 0.0f;
    #pragma unroll
    for (int c = 0; c < 4; ++c) {
        v[c] = rp[lane * 4 + c];
        ss += v[c].x * v[c].x + v[c].y * v[c].y + v[c].z * v[c].z + v[c].w * v[c].w;
    }
    #pragma unroll
    for (int off = 1; off < 64; off <<= 1) ss += __shfl_xor(ss, off, 64);
    const float inv = FP8_SCALE / sqrtf(fmaxf(ss, 1e-24f));

    i32x4 pk;
    #pragma unroll
    for (int c = 0; c < 4; ++c) {
        int w0 = __builtin_amdgcn_cvt_pk_fp8_f32(v[c].x * inv, v[c].y * inv, 0, false);
        w0     = __builtin_amdgcn_cvt_pk_fp8_f32(v[c].z * inv, v[c].w * inv, w0, true);
        pk[c] = w0;
    }
    ((i32x4*)orow)[lane] = pk;
}

// ---------------- MX-fp8 GEMM 128x128, BK=128, 16x16x128 scaled MFMA + distance epilogue ---
// LDS tile [128 rows][128 B]; row stride 128 B = 32 banks. 16B granule g (0..7) stored at
// phys slot (g ^ (row&7)) -> both staging and frag reads are 2-way (free).
__global__ __launch_bounds__(256) void gemm_dist(
    const unsigned char* __restrict__ A,
    const unsigned char* __restrict__ Bp,
    __hip_bfloat16* __restrict__ D,
    float* __restrict__ rowsum)
{
    __shared__ unsigned char As[128 * 128];   // 16 KB
    __shared__ unsigned char Bs[128 * 128];   // 16 KB

    const int tid  = threadIdx.x;
    const int lane = tid & 63;
    const int wave = tid >> 6;

    // XCD swizzle: the 8 bn-blocks of one bm share id%8 (same XCD) for A-tile L2 reuse
    const int id  = blockIdx.x;             // 0..1023
    const int xcd = id & 7;
    const int seq = id >> 3;                // 0..127
    const int bn  = seq & 7;                // 0..7
    const int bm  = xcd * 16 + (seq >> 3);  // 0..127

    const int waveM = (wave >> 1) * 64;
    const int waveN = (wave & 1) * 64;

    f32x4 acc[4][4] = {};

    // staging: round r covers rows [r*32, r*32+32); wave w -> rows r*32+w*8 .. +8
    // lane i -> row +(i>>3), phys granule i&7, fetching logical granule (i&7)^(i>>3)
    const int srow8 = lane >> 3;
    const int sg    = (lane & 7) ^ srow8;
    const unsigned char* Abase = A  + ((size_t)(bm * 128 + wave * 8 + srow8)) * FDIM + sg * 16;
    const unsigned char* Bbase = Bp + ((size_t)(bn * 128 + wave * 8 + srow8)) * FDIM + sg * 16;

    // frag addressing: R = waveX + mt*16 + (lane&15); R&7 = lane&7.
    // logical granules for this lane: 2q, 2q+1 (q = lane>>4); phys = g ^ (lane&7)
    const int q2   = (lane >> 4) * 2;
    const int bxor = lane & 7;
    const int fA = (waveM + (lane & 15)) * 128;
    const int fB = (waveN + (lane & 15)) * 128;
    const int pg0 = ((q2)     ^ bxor) * 16;
    const int pg1 = ((q2 + 1) ^ bxor) * 16;

    #pragma unroll 1
    for (int k0 = 0; k0 < FDIM; k0 += 128) {
        __syncthreads();
        #pragma unroll
        for (int r = 0; r < 4; ++r) {
            GLD_LDS(Abase + (size_t)(r * 32) * FDIM + k0, &As[(r * 32 + wave * 8) * 128]);
            GLD_LDS(Bbase + (size_t)(r * 32) * FDIM + k0, &Bs[(r * 32 + wave * 8) * 128]);
        }
        __syncthreads();

        i32x8 b[4];
        #pragma unroll
        for (int nt = 0; nt < 4; ++nt) {
            const i32x4 lo = *(const i32x4*)&Bs[fB + nt * 2048 + pg0];
            const i32x4 hi = *(const i32x4*)&Bs[fB + nt * 2048 + pg1];
            b[nt] = (i32x8){lo.x, lo.y, lo.z, lo.w, hi.x, hi.y, hi.z, hi.w};
        }
        #pragma unroll
        for (int mt = 0; mt < 4; ++mt) {
            const i32x4 lo = *(const i32x4*)&As[fA + mt * 2048 + pg0];
            const i32x4 hi = *(const i32x4*)&As[fA + mt * 2048 + pg1];
            const i32x8 a = (i32x8){lo.x, lo.y, lo.z, lo.w, hi.x, hi.y, hi.z, hi.w};
            #pragma unroll
            for (int nt = 0; nt < 4; ++nt)
                acc[mt][nt] = __builtin_amdgcn_mfma_scale_f32_16x16x128_f8f6f4(
                    a, b[nt], acc[mt][nt], 0, 0, /*opsel_a*/0, /*scale_a*/127, /*opsel_b*/0, /*scale_b*/127);
        }
    }

    // epilogue: sim = acc/65536; d = sqrt(max(1-sim,0)); C/D: col=lane&15, row=(lane>>4)*4+reg
    const int row0 = bm * 128 + waveM;
    const int col0 = bn * 128 + waveN;
    #pragma unroll
    for (int mt = 0; mt < 4; ++mt) {
        #pragma unroll
        for (int r = 0; r < 4; ++r) {
            const int row = row0 + mt * 16 + (lane >> 4) * 4 + r;
            float part = 0.0f;
            #pragma unroll
            for (int nt = 0; nt < 4; ++nt) {
                const int col = col0 + nt * 16 + (lane & 15);
                const float sim = acc[mt][nt][r] * INV_SIM;
                const float dv = sqrtf(fmaxf(1.0f - sim, 0.0f));
                if (col < C_COLS) {
                    D[(size_t)row * C_COLS + col] = __float2bfloat16(dv);
                    part += dv;
                }
            }
            part += __shfl_xor(part, 1, 64);
            part += __shfl_xor(part, 2, 64);
            part += __shfl_xor(part, 4, 64);
            part += __shfl_xor(part, 8, 64);
            if ((lane & 15) == 0) atomicAdd(&rowsum[row], part);
        }
    }
}

// ---------------- finalize: out = (-|ds|/T) * (d + rowsum/1000) ----------------
__global__ __launch_bounds__(256) void finalize(
    const __hip_bfloat16* __restrict__ D, const float* __restrict__ rowsum,
    const float* __restrict__ scale, const float* __restrict__ temp,
    float* __restrict__ out)
{
    const size_t i = (size_t)blockIdx.x * 256 + threadIdx.x;   // 8-element group
    const float a = -fabsf(scale[0]) / temp[0];
    const int row = (int)((i * 8) / C_COLS);                   // 1000 % 8 == 0, no straddle
    const float m = rowsum[row] * (1.0f / (float)C_COLS);

    const bf16x8 dv = *(const bf16x8*)(D + i * 8);
    const __hip_bfloat16* dp = (const __hip_bfloat16*)&dv;
    float4 o0, o1;
    o0.x = a * (__bfloat162float(dp[0]) + m);
    o0.y = a * (__bfloat162float(dp[1]) + m);
    o0.z = a * (__bfloat162float(dp[2]) + m);
    o0.w = a * (__bfloat162float(dp[3]) + m);
    o1.x = a * (__bfloat162float(dp[4]) + m);
    o1.y = a * (__bfloat162float(dp[5]) + m);
    o1.z = a * (__bfloat162float(dp[6]) + m);
    o1.w = a * (__bfloat162float(dp[7]) + m);
    ((float4*)out)[i * 2]     = o0;
    ((float4*)out)[i * 2 + 1] = o1;
}

extern "C" void kernel_launch(void* const* d_in, const int* in_sizes, int n_in,
                              void* d_out, int out_size, void* d_ws, size_t ws_size,
                              hipStream_t stream)
{
    const float* features = (const float*)d_in[0];   // [16384,1024]
    const float* protos   = (const float*)d_in[1];   // [1000,1024]
    const float* dscale   = (const float*)d_in[2];   // [1]
    const float* temp     = (const float*)d_in[3];   // [1]
    float* out = (float*)d_out;                      // [16384,1000]

    char* ws = (char*)d_ws;
    unsigned char* fb = (unsigned char*)ws;                       // 16,777,216 B
    unsigned char* pb = (unsigned char*)(ws + 16777216);          //  1,048,576 B
    __hip_bfloat16* D = (__hip_bfloat16*)(ws + 17825792);         // 32,768,000 B
    float* rowsum     = (float*)(ws + 50593792);                  //     65,536 B

    normalize_all<<<FBLKS + C_PAD / 4, 256, 0, stream>>>(features, protos, fb, pb, rowsum);

    gemm_dist<<<1024, 256, 0, stream>>>(fb, pb, D, rowsum);

    finalize<<<(B_ROWS * C_COLS / 8) / 256, 256, 0, stream>>>(D, rowsum, dscale, temp, out);
}